// Round 1
// 335.853 us; speedup vs baseline: 1.0645x; 1.0645x over previous
//
#include <hip/hip_runtime.h>
#include <math.h>

#define BB 32
#define CC 768
#define HWN 1024
#define DD 384
#define KK 64
#define EPSI 20.0f            // 1/eps
#define NORMC (-6.9920964f)   // -log(1088)
#define NITERS 10

typedef __bf16 bf16;
typedef bf16 bf16x8 __attribute__((ext_vector_type(8)));
typedef bf16 bf16x4 __attribute__((ext_vector_type(4)));
typedef float f32x4 __attribute__((ext_vector_type(4)));
typedef _Float16 f16;
typedef f16 f16x2 __attribute__((ext_vector_type(2)));
typedef f16 f16x4 __attribute__((ext_vector_type(4)));

__device__ __forceinline__ float wave_sum(float v){
  #pragma unroll
  for (int off = 32; off; off >>= 1) v += __shfl_xor(v, off, 64);
  return v;
}
__device__ __forceinline__ float wave_max(float v){
  #pragma unroll
  for (int off = 32; off; off >>= 1) v = fmaxf(v, __shfl_xor(v, off, 64));
  return v;
}

__device__ __forceinline__ void async16(const bf16* g, bf16* l){
  __builtin_amdgcn_global_load_lds((const __attribute__((address_space(1))) unsigned int*)g,
                                   (__attribute__((address_space(3))) unsigned int*)l,
                                   16, 0, 0);
}

// ---------------- K0: normalize codebook rows v[64][384] -> clusters ----------------
__global__ __launch_bounds__(256) void k0_clusters(const float* __restrict__ vin,
                                                   float* __restrict__ clus){
  int w = threadIdx.x >> 6, l = threadIdx.x & 63;
  int k = blockIdx.x * 4 + w;               // 16 blocks * 4 waves = 64 rows
  float s = 0.f;
  #pragma unroll
  for (int i = 0; i < 6; i++){ float x = vin[k*DD + l + 64*i]; s += x*x; }
  s = wave_sum(s);
  float scale = 1.f / fmaxf(sqrtf(s), 1e-12f);
  #pragma unroll
  for (int i = 0; i < 6; i++) clus[k*DD + l + 64*i] = vin[k*DD + l + 64*i] * scale;
}

// ---------------- KW: convert conv_w fp32[384][768] -> bf16 ----------------
__global__ __launch_bounds__(256) void k_wconv(const float* __restrict__ w,
                                               bf16* __restrict__ wb){
  int i = (blockIdx.x * 256 + threadIdx.x) * 4;
  float4 v = *(const float4*)&w[i];
  bf16x4 o;
  o[0] = (bf16)v.x; o[1] = (bf16)v.y; o[2] = (bf16)v.z; o[3] = (bf16)v.w;
  *(bf16x4*)&wb[i] = o;
}

// ---------------- KXT: X[b][768][1024] fp32 -> Xt[b][1024][768] bf16 (transpose) -----
__global__ __launch_bounds__(256) void k_xt(const float* __restrict__ x,
                                            bf16* __restrict__ xt){
  __shared__ float S[64][68];
  int b  = blockIdx.z;
  int k0 = blockIdx.y * 64;   // channel dim
  int n0 = blockIdx.x * 64;   // spatial dim
  const float* X = x + (size_t)b * CC * HWN;
  int t = threadIdx.x;
  int rr = t >> 4, cc = (t & 15) * 4;
  #pragma unroll
  for (int it = 0; it < 4; it++){
    float4 v = *(const float4*)&X[(size_t)(k0 + rr + it*16)*HWN + n0 + cc];
    *(float4*)&S[rr + it*16][cc] = v;
  }
  __syncthreads();
  int n = t >> 2, kc = t & 3;
  bf16* orow = xt + (size_t)b * HWN * CC + (size_t)(n0 + n) * CC + k0;
  #pragma unroll
  for (int half = 0; half < 2; half++){
    int kb = half*32 + kc*8;
    bf16x8 o;
    #pragma unroll
    for (int jj = 0; jj < 8; jj++){
      int j = (jj + kc) & 7;   // rotate read order to dodge bank conflicts
      o[j] = (bf16)S[kb + j][n];
    }
    *(bf16x8*)&orow[kb] = o;
  }
}

// ---------------- K1: MFMA GEMM  xp[b][n][m] = sum_k Xt[b][n][k] * Wb[m][k] + bias[m]
__global__ __launch_bounds__(256) void k_gemm(const bf16* __restrict__ Wb,
                                              const bf16* __restrict__ Xt,
                                              const float* __restrict__ bias,
                                              float* __restrict__ xp){
  __shared__ bf16 Wl[4][128][8];   // [kquad][row(m)][8 bf16]  8 KB
  __shared__ bf16 Xl[4][128][8];   // [kquad][row(n)][8 bf16]  8 KB
  int b  = blockIdx.z;
  int m0 = blockIdx.y * 128;
  int n0 = blockIdx.x * 128;
  int t = threadIdx.x, wv = t >> 6, l = t & 63;
  int l15 = l & 15, quad = l >> 4;
  int wn = wv >> 1, wm = wv & 1;
  const bf16* Xb = Xt + (size_t)b * HWN * CC;

  int kqA = wv >> 1;
  int rb  = (wv & 1) * 64;
  const bf16* gW0 = Wb + (size_t)(m0 + rb + l) * CC + kqA * 8;
  const bf16* gX0 = Xb + (size_t)(n0 + rb + l) * CC + kqA * 8;
  bf16* lW0 = &Wl[0][0][0] + wv * 512;
  bf16* lX0 = &Xl[0][0][0] + wv * 512;

  f32x4 acc[4][4];
  const f32x4 zero = {0.f, 0.f, 0.f, 0.f};
  #pragma unroll
  for (int i = 0; i < 4; i++)
    #pragma unroll
    for (int j = 0; j < 4; j++) acc[i][j] = zero;

  for (int k0 = 0; k0 < CC; k0 += 32){
    async16(gW0 + k0,      lW0);
    async16(gW0 + k0 + 16, lW0 + 2048);
    async16(gX0 + k0,      lX0);
    async16(gX0 + k0 + 16, lX0 + 2048);
    __syncthreads();
    bf16x8 xf[4], wf[4];
    #pragma unroll
    for (int i = 0; i < 4; i++)
      xf[i] = *(const bf16x8*)&Xl[quad][wn*64 + i*16 + l15][0];
    #pragma unroll
    for (int j = 0; j < 4; j++)
      wf[j] = *(const bf16x8*)&Wl[quad][wm*64 + j*16 + l15][0];
    #pragma unroll
    for (int i = 0; i < 4; i++)
      #pragma unroll
      for (int j = 0; j < 4; j++)
        acc[i][j] = __builtin_amdgcn_mfma_f32_16x16x32_bf16(xf[i], wf[j], acc[i][j], 0, 0, 0);
    __syncthreads();
  }

  float bb[4];
  #pragma unroll
  for (int j = 0; j < 4; j++) bb[j] = bias[m0 + wm*64 + j*16 + l15];
  #pragma unroll
  for (int i = 0; i < 4; i++){
    int nb = n0 + wn*64 + i*16 + quad*4;
    #pragma unroll
    for (int r = 0; r < 4; r++){
      float* orow = xp + ((size_t)b * HWN + nb + r) * DD;
      #pragma unroll
      for (int j = 0; j < 4; j++){
        int m = m0 + wm*64 + j*16 + l15;
        orow[m] = acc[i][j][r] + bb[j];
      }
    }
  }
}

// ---------------- K2: per-token 1/max(||x_proj||,1e-12) ----------------
__global__ __launch_bounds__(256) void k2_rnorm(const float* __restrict__ xp,
                                                float* __restrict__ rn){
  int w = threadIdx.x >> 6, l = threadIdx.x & 63;
  int t = blockIdx.x * 4 + w;               // 0..32767
  const float* row = xp + (size_t)t * DD;
  float s = 0.f;
  #pragma unroll
  for (int i = 0; i < 6; i++){ float xv = row[l + 64*i]; s += xv*xv; }
  s = wave_sum(s);
  if (l == 0) rn[t] = 1.f / fmaxf(sqrtf(s), 1e-12f);
}

// ---------------- KXPT: XpT[b][d][n] = bf16( xp[b][n][d] * rn[b*1024+n] )  (xn^T) ----
// Feeds k5_mfma's B operand: both MFMA operands need [row][contraction(n)] layout.
// Aliased over Xt (dead after k_gemm). ~75 MB traffic, memory-bound.
__global__ __launch_bounds__(256) void k_xpt(const float* __restrict__ xp,
                                             const float* __restrict__ rn,
                                             bf16* __restrict__ xpt){
  __shared__ float S[64][68];
  int b  = blockIdx.z;
  int d0 = blockIdx.y * 64;
  int n0 = blockIdx.x * 64;
  const float* xpb = xp + (size_t)b * HWN * DD;
  const float* rnb = rn + (size_t)b * HWN;
  int t = threadIdx.x;
  int rr = t >> 4, cc = (t & 15) * 4;
  #pragma unroll
  for (int it = 0; it < 4; it++){
    int row = rr + it*16;
    float sc = rnb[n0 + row];
    float4 v = *(const float4*)&xpb[(size_t)(n0 + row)*DD + d0 + cc];
    v.x *= sc; v.y *= sc; v.z *= sc; v.w *= sc;
    *(float4*)&S[row][cc] = v;
  }
  __syncthreads();
  int d = t >> 2, c0 = (t & 3) * 16;   // lanes 0..3 cover 64 consecutive n of row d
  bf16* orow = xpt + (size_t)b * DD * HWN + (size_t)(d0 + d) * HWN + n0 + c0;
  bf16x8 o0, o1;
  #pragma unroll
  for (int jj = 0; jj < 8; jj++) o0[jj] = (bf16)S[c0 + jj][d];
  #pragma unroll
  for (int jj = 0; jj < 8; jj++) o1[jj] = (bf16)S[c0 + 8 + jj][d];
  *(bf16x8*)&orow[0] = o0;
  *(bf16x8*)&orow[8] = o1;
}

// ---------------- K3: Z[b][k][n] = (clusters @ x_proj_b^T) * rnorm[n] / eps ----------
__global__ __launch_bounds__(256) void k3_scores(const float* __restrict__ clus,
                                                 const float* __restrict__ xp,
                                                 const float* __restrict__ rn,
                                                 float* __restrict__ Z){
  __shared__ float As[16][68];  // [dd][k]
  __shared__ float Bs[16][68];  // [dd][n]
  int b = blockIdx.y, n0 = blockIdx.x * 64;
  const float* xpb = xp + (size_t)b * HWN * DD;
  int tid = threadIdx.x, ty = tid >> 4, tx = tid & 15;
  float acc[4][4] = {};
  for (int d0 = 0; d0 < DD; d0 += 16){
    {
      int k = tid >> 2, q = tid & 3;
      const float4 a4 = *(const float4*)&clus[(size_t)k*DD + d0 + q*4];
      As[q*4+0][k] = a4.x; As[q*4+1][k] = a4.y; As[q*4+2][k] = a4.z; As[q*4+3][k] = a4.w;
    }
    {
      int nn = tid >> 2, q = tid & 3;
      const float4 x4 = *(const float4*)&xpb[(size_t)(n0+nn)*DD + d0 + q*4];
      Bs[q*4+0][nn] = x4.x; Bs[q*4+1][nn] = x4.y; Bs[q*4+2][nn] = x4.z; Bs[q*4+3][nn] = x4.w;
    }
    __syncthreads();
    #pragma unroll
    for (int kk = 0; kk < 16; kk++){
      const float4 a4 = *(const float4*)&As[kk][ty*4];
      const float4 b4 = *(const float4*)&Bs[kk][tx*4];
      const float av[4] = {a4.x, a4.y, a4.z, a4.w};
      const float bv[4] = {b4.x, b4.y, b4.z, b4.w};
      #pragma unroll
      for (int i = 0; i < 4; i++)
        #pragma unroll
        for (int j = 0; j < 4; j++)
          acc[i][j] = fmaf(av[i], bv[j], acc[i][j]);
    }
    __syncthreads();
  }
  const float* rnb = rn + (size_t)b * HWN;
  #pragma unroll
  for (int i = 0; i < 4; i++){
    int k = ty*4 + i;
    int n = n0 + tx*4;
    float4 o;
    o.x = acc[i][0] * rnb[n+0] * EPSI;
    o.y = acc[i][1] * rnb[n+1] * EPSI;
    o.z = acc[i][2] * rnb[n+2] * EPSI;
    o.w = acc[i][3] * rnb[n+3] * EPSI;
    *(float4*)&Z[((size_t)b*KK + k)*HWN + n] = o;
  }
}

// ---------------- K4: Sinkhorn, one 1024-thr block per batch, E=exp(Z-rmax) in f16 LDS
// u[r] = NORMC - rmax[r] - log(sum_n E[r][n]*ev[n]);  eu[r] = exp(NORMC)/sum  (exact)
// v[c] = NORMC - log(sum_m E[m][c]*eu[m]);            ev[c] = exp(v[c])
// NOTE: v reaches ~+12 here (asymmetric marginals 64 vs 1024), so ev MUST be fp32 —
// f16 ev (max 65504 = e^11.09) overflowed to Inf in R3 and cascaded to NaN.
// E in (0,1] is always f16-safe. ~145 KB LDS (gfx950: 160 KB/CU).
__global__ __launch_bounds__(1024) void k4_sinkhorn(const float* __restrict__ Z,
                                                    float* __restrict__ U,
                                                    float* __restrict__ V){
  __shared__ f16  E[64][1024];    // 128 KB
  __shared__ float evf[1024];     // exp(v), fp32 (overflow-safe)
  __shared__ float eu[64];
  __shared__ float rmax[64];
  __shared__ float u_l[64];
  __shared__ float v_l[1024];
  __shared__ float sp[2][1024];   // v-phase partials per column (two row-halves)
  int b = blockIdx.x;
  const float* Zb = Z + (size_t)b * KK * HWN;
  int t = threadIdx.x, w = t >> 6, l = t & 63;

  // ---- stage: wave w owns rows 4w..4w+3; compute rowmax, E = f16(exp(Z - rmax))
  #pragma unroll
  for (int rr = 0; rr < 4; rr++){
    int r = w*4 + rr;
    float4 z[4];
    float mx = -INFINITY;
    #pragma unroll
    for (int j = 0; j < 4; j++){
      z[j] = *(const float4*)&Zb[(size_t)r*HWN + 4*l + 256*j];
      mx = fmaxf(mx, fmaxf(fmaxf(z[j].x, z[j].y), fmaxf(z[j].z, z[j].w)));
    }
    mx = wave_max(mx);
    if (l == 0) rmax[r] = mx;
    #pragma unroll
    for (int j = 0; j < 4; j++){
      f16x4 e4;
      e4[0] = (f16)__expf(z[j].x - mx); e4[1] = (f16)__expf(z[j].y - mx);
      e4[2] = (f16)__expf(z[j].z - mx); e4[3] = (f16)__expf(z[j].w - mx);
      *(f16x4*)&E[r][4*l + 256*j] = e4;
    }
  }
  evf[t] = 1.f;
  v_l[t] = 0.f;
  __syncthreads();

  for (int it = 0; it < NITERS; it++){
    // ---- u-phase: wave w -> rows 4w..4w+3; lane l covers col-pairs p = l+64j
    float evx[16];
    #pragma unroll
    for (int j = 0; j < 8; j++){
      float2 e2 = *(const float2*)&evf[2*(l + 64*j)];
      evx[2*j] = e2.x; evx[2*j+1] = e2.y;
    }
    float us[4];
    #pragma unroll
    for (int rr = 0; rr < 4; rr++){
      int r = w*4 + rr;
      float s = 0.f;
      #pragma unroll
      for (int j = 0; j < 8; j++){
        f16x2 e2 = *(const f16x2*)&E[r][2*(l + 64*j)];
        s = fmaf((float)e2[0], evx[2*j],   s);
        s = fmaf((float)e2[1], evx[2*j+1], s);
      }
      us[rr] = wave_sum(s);
    }
    if (l == 0){
      #pragma unroll
      for (int rr = 0; rr < 4; rr++){
        int r = w*4 + rr;
        u_l[r] = NORMC - rmax[r] - __logf(us[rr]);
        eu[r]  = __expf(NORMC) / us[rr];      // = exp(u+rmax), no transcendental
      }
    }
    __syncthreads();
    // ---- v-phase: thread t -> col pair p = t&511, row half h = t>>9
    {
      int p = t & 511, h = t >> 9;
      float sx = 0.f, sy = 0.f;
      #pragma unroll
      for (int mq = 0; mq < 8; mq++){
        float4 eu4 = *(const float4*)&eu[h*32 + mq*4];
        const float euv[4] = {eu4.x, eu4.y, eu4.z, eu4.w};
        #pragma unroll
        for (int i = 0; i < 4; i++){
          f16x2 e2 = *(const f16x2*)&E[h*32 + mq*4 + i][2*p];
          sx = fmaf((float)e2[0], euv[i], sx);
          sy = fmaf((float)e2[1], euv[i], sy);
        }
      }
      float2 o; o.x = sx; o.y = sy;
      *(float2*)&sp[h][2*p] = o;
    }
    __syncthreads();
    if (t < 512){
      int p = t;
      float2 a = *(const float2*)&sp[0][2*p];
      float2 c = *(const float2*)&sp[1][2*p];
      float vx = NORMC - __logf(a.x + c.x);
      float vy = NORMC - __logf(a.y + c.y);
      v_l[2*p]   = vx;
      v_l[2*p+1] = vy;
      float2 ee; ee.x = __expf(vx); ee.y = __expf(vy);
      *(float2*)&evf[2*p] = ee;
    }
    __syncthreads();
  }
  V[b*HWN + t] = v_l[t];
  if (t < 64) U[b*KK + t] = u_l[t];
}

// ---------------- K5 (MFMA, split-K over n): out[b][k][d] += sum_n E'[k][n]*XpT[d][n]
// E'[k][n] = exp(Z+u+v-NORMC) in bf16 (rn already folded into XpT).
// Grid (8 chunks x 32 b) = 256 blocks; 4 n-steps of 32 per block; atomic partials.
// LDS rows padded to 40 bf16 (80 B): row stride = 20 banks -> worst 2-way aliasing
// on both ds_write_b128 and b128 frag reads (2-way is free per m136).
__global__ __launch_bounds__(256) void k5_mfma(const float* __restrict__ Z,
                                               const float* __restrict__ U,
                                               const float* __restrict__ V,
                                               const bf16* __restrict__ XpT,
                                               float* __restrict__ out){
  __shared__ bf16 El[64][40];     // 5 KB   [k][n-step]
  __shared__ bf16 Xl[384][40];    // 30 KB  [d][n-step]
  int b  = blockIdx.y;
  int nsb = blockIdx.x * 128;     // n-chunk base
  const float* Zb = Z + (size_t)b * KK * HWN;
  const bf16*  Xb = XpT + (size_t)b * DD * HWN;
  const float* Vb = V + (size_t)b * HWN;
  int t = threadIdx.x, wv = t >> 6, l = t & 63;
  int l15 = l & 15, quad = l >> 4;
  int er = t >> 2, ec0 = (t & 3) * 8;         // E-stage: row, col-offset (fixed/thread)
  float ur = U[b*KK + er];

  f32x4 acc[4][6];
  const f32x4 zero = {0.f, 0.f, 0.f, 0.f};
  #pragma unroll
  for (int i = 0; i < 4; i++)
    #pragma unroll
    for (int j = 0; j < 6; j++) acc[i][j] = zero;

  for (int st = 0; st < 4; st++){
    int n0 = nsb + st*32;
    // ---- stage E' = bf16(exp(Z + u + v - NORMC)) : 64x32
    {
      float4 z0 = *(const float4*)&Zb[(size_t)er*HWN + n0 + ec0];
      float4 z1 = *(const float4*)&Zb[(size_t)er*HWN + n0 + ec0 + 4];
      float4 v0 = *(const float4*)&Vb[n0 + ec0];
      float4 v1 = *(const float4*)&Vb[n0 + ec0 + 4];
      bf16x8 e;
      e[0] = (bf16)__expf(z0.x + ur + v0.x - NORMC);
      e[1] = (bf16)__expf(z0.y + ur + v0.y - NORMC);
      e[2] = (bf16)__expf(z0.z + ur + v0.z - NORMC);
      e[3] = (bf16)__expf(z0.w + ur + v0.w - NORMC);
      e[4] = (bf16)__expf(z1.x + ur + v1.x - NORMC);
      e[5] = (bf16)__expf(z1.y + ur + v1.y - NORMC);
      e[6] = (bf16)__expf(z1.z + ur + v1.z - NORMC);
      e[7] = (bf16)__expf(z1.w + ur + v1.w - NORMC);
      *(bf16x8*)&El[er][ec0] = e;
    }
    // ---- stage XpT slab: 384 rows x 32 n (bf16, pure copy); 6 x 16B per thread
    #pragma unroll
    for (int ii = 0; ii < 6; ii++){
      int chunk = t + 256*ii;
      int d = chunk >> 2, cb = (chunk & 3) * 8;
      bf16x8 xv = *(const bf16x8*)&Xb[(size_t)d*HWN + n0 + cb];
      *(bf16x8*)&Xl[d][cb] = xv;
    }
    __syncthreads();
    bf16x8 af[4], bfr[6];
    #pragma unroll
    for (int i = 0; i < 4; i++)
      af[i] = *(const bf16x8*)&El[i*16 + l15][quad*8];
    #pragma unroll
    for (int j = 0; j < 6; j++)
      bfr[j] = *(const bf16x8*)&Xl[wv*96 + j*16 + l15][quad*8];
    #pragma unroll
    for (int i = 0; i < 4; i++)
      #pragma unroll
      for (int j = 0; j < 6; j++)
        acc[i][j] = __builtin_amdgcn_mfma_f32_16x16x32_bf16(af[i], bfr[j], acc[i][j], 0, 0, 0);
    __syncthreads();
  }

  // ---- epilogue: atomic partial add (out zeroed by hipMemsetAsync)
  float* ob = out + (size_t)b * KK * DD;
  #pragma unroll
  for (int i = 0; i < 4; i++){
    int kbase = i*16 + quad*4;
    #pragma unroll
    for (int j = 0; j < 6; j++){
      int d = wv*96 + j*16 + l15;
      #pragma unroll
      for (int r = 0; r < 4; r++)
        unsafeAtomicAdd(&ob[(size_t)(kbase + r)*DD + d], acc[i][j][r]);
    }
  }
}

extern "C" void kernel_launch(void* const* d_in, const int* in_sizes, int n_in,
                              void* d_out, int out_size, void* d_ws, size_t ws_size,
                              hipStream_t stream) {
  const float* x      = (const float*)d_in[0];   // [32,768,32,32]
  const float* conv_w = (const float*)d_in[1];   // [384,768]
  const float* conv_b = (const float*)d_in[2];   // [384]
  const float* vcode  = (const float*)d_in[3];   // [64,384]
  float* out = (float*)d_out;
  float* vt_out = out;                 // [32,64,384]  = 786432
  float* xp_out = out + 786432;        // [32,1024,384]

  bf16* Xt   = (bf16*)d_ws;                          // 25165824 elems (50.3 MB)
  bf16* Wb   = Xt + (size_t)BB * HWN * CC;           // 294912 elems (0.6 MB)
  float* clus = (float*)(Wb + (size_t)DD * CC);      // 24576
  float* Zbuf = clus + 24576;                        // 2097152
  float* Ubuf = Zbuf + 2097152;                      // 2048
  float* Vbuf = Ubuf + 2048;                         // 32768
  float* Rn   = Vbuf + 32768;                        // 32768
  bf16* XpT  = Xt;   // alias: Xt is dead after k_gemm; XpT = xn^T bf16 [32][384][1024]

  hipMemsetAsync(vt_out, 0, (size_t)786432 * sizeof(float), stream);
  k0_clusters<<<16, 256, 0, stream>>>(vcode, clus);
  k_wconv<<<288, 256, 0, stream>>>(conv_w, Wb);
  k_xt<<<dim3(16, 12, 32), 256, 0, stream>>>(x, Xt);
  k_gemm<<<dim3(8, 3, 32), 256, 0, stream>>>(Wb, Xt, conv_b, xp_out);
  k2_rnorm<<<8192, 256, 0, stream>>>(xp_out, Rn);
  k_xpt<<<dim3(16, 6, 32), 256, 0, stream>>>(xp_out, Rn, XpT);
  k3_scores<<<dim3(16, 32), 256, 0, stream>>>(clus, xp_out, Rn, Zbuf);
  k4_sinkhorn<<<32, 1024, 0, stream>>>(Zbuf, Ubuf, Vbuf);
  k5_mfma<<<dim3(8, 32), 256, 0, stream>>>(Zbuf, Ubuf, Vbuf, XpT, vt_out);
}

// Round 2
// 310.124 us; speedup vs baseline: 1.1528x; 1.0830x over previous
//
#include <hip/hip_runtime.h>
#include <math.h>

#define BB 32
#define CC 768
#define HWN 1024
#define DD 384
#define KK 64
#define EPSI 20.0f            // 1/eps
#define NORMC (-6.9920964f)   // -log(1088)
#define NITERS 10

typedef __bf16 bf16;
typedef bf16 bf16x8 __attribute__((ext_vector_type(8)));
typedef bf16 bf16x4 __attribute__((ext_vector_type(4)));
typedef float f32x4 __attribute__((ext_vector_type(4)));
typedef _Float16 f16;
typedef f16 f16x2 __attribute__((ext_vector_type(2)));
typedef f16 f16x4 __attribute__((ext_vector_type(4)));

__device__ __forceinline__ float wave_sum(float v){
  #pragma unroll
  for (int off = 32; off; off >>= 1) v += __shfl_xor(v, off, 64);
  return v;
}
__device__ __forceinline__ float wave_max(float v){
  #pragma unroll
  for (int off = 32; off; off >>= 1) v = fmaxf(v, __shfl_xor(v, off, 64));
  return v;
}

__device__ __forceinline__ void async16(const bf16* g, bf16* l){
  __builtin_amdgcn_global_load_lds((const __attribute__((address_space(1))) unsigned int*)g,
                                   (__attribute__((address_space(3))) unsigned int*)l,
                                   16, 0, 0);
}

// ---------------- K0: normalize codebook rows v[64][384] -> clusb (bf16) ------------
__global__ __launch_bounds__(256) void k0_clusters(const float* __restrict__ vin,
                                                   bf16* __restrict__ clusb){
  int w = threadIdx.x >> 6, l = threadIdx.x & 63;
  int k = blockIdx.x * 4 + w;               // 16 blocks * 4 waves = 64 rows
  float s = 0.f;
  #pragma unroll
  for (int i = 0; i < 6; i++){ float x = vin[k*DD + l + 64*i]; s += x*x; }
  s = wave_sum(s);
  float scale = 1.f / fmaxf(sqrtf(s), 1e-12f);
  #pragma unroll
  for (int i = 0; i < 6; i++) clusb[k*DD + l + 64*i] = (bf16)(vin[k*DD + l + 64*i] * scale);
}

// ---------------- KW: convert conv_w fp32[384][768] -> bf16 ----------------
__global__ __launch_bounds__(256) void k_wconv(const float* __restrict__ w,
                                               bf16* __restrict__ wb){
  int i = (blockIdx.x * 256 + threadIdx.x) * 4;
  float4 v = *(const float4*)&w[i];
  bf16x4 o;
  o[0] = (bf16)v.x; o[1] = (bf16)v.y; o[2] = (bf16)v.z; o[3] = (bf16)v.w;
  *(bf16x4*)&wb[i] = o;
}

// ---------------- KXT: X[b][768][1024] fp32 -> Xt[b][1024][768] bf16 (transpose) -----
__global__ __launch_bounds__(256) void k_xt(const float* __restrict__ x,
                                            bf16* __restrict__ xt){
  __shared__ float S[64][68];
  int b  = blockIdx.z;
  int k0 = blockIdx.y * 64;   // channel dim
  int n0 = blockIdx.x * 64;   // spatial dim
  const float* X = x + (size_t)b * CC * HWN;
  int t = threadIdx.x;
  int rr = t >> 4, cc = (t & 15) * 4;
  #pragma unroll
  for (int it = 0; it < 4; it++){
    float4 v = *(const float4*)&X[(size_t)(k0 + rr + it*16)*HWN + n0 + cc];
    *(float4*)&S[rr + it*16][cc] = v;
  }
  __syncthreads();
  int n = t >> 2, kc = t & 3;
  bf16* orow = xt + (size_t)b * HWN * CC + (size_t)(n0 + n) * CC + k0;
  #pragma unroll
  for (int half = 0; half < 2; half++){
    int kb = half*32 + kc*8;
    bf16x8 o;
    #pragma unroll
    for (int jj = 0; jj < 8; jj++){
      int j = (jj + kc) & 7;   // rotate read order to dodge bank conflicts
      o[j] = (bf16)S[kb + j][n];
    }
    *(bf16x8*)&orow[kb] = o;
  }
}

// ---------------- K1: MFMA GEMM, full-m blocks: xp[b][n][m] = Xt[b][n][:]*Wb[m][:] + bias
// Grid (8 n-chunks x 32 b) = 256 blocks, 512 thr (8 waves = 2n x 4m).
// Xt read ONCE (50 MB, was 3x); W (0.6 MB) streams from L2.
// LDS per K-step(32): Wl 384x32 bf16 = 24 KB, Xl 128x32 = 8 KB. Layout [row][kq][8]:
// chunk c (16B) -> row=c>>2, kq=c&3, LDS elem offset = c*8 (linear in lane order for
// global_load_lds). Frag reads are contiguous 1KB per (row-group, quad) -> conflict-free.
__global__ __launch_bounds__(512) void k_gemm(const bf16* __restrict__ Wb,
                                              const bf16* __restrict__ Xt,
                                              const float* __restrict__ bias,
                                              float* __restrict__ xp){
  __shared__ bf16 Wl[384][4][8];   // 24 KB
  __shared__ bf16 Xl[128][4][8];   // 8 KB
  int b  = blockIdx.y;
  int n0 = blockIdx.x * 128;
  int t = threadIdx.x, wv = t >> 6, l = t & 63;
  int l15 = l & 15, quad = l >> 4;
  int wn = wv >> 2, wm = wv & 3;
  const bf16* Xb = Xt + (size_t)b * HWN * CC;

  int rbase = wv*16 + (l >> 2);
  int kq8   = (l & 3) * 8;
  const bf16* gX = Xb + (size_t)(n0 + rbase) * CC + kq8;
  const bf16* gW = Wb + (size_t)rbase * CC + kq8;
  bf16* lX = &Xl[0][0][0] + wv * 512;
  bf16* lW = &Wl[0][0][0] + wv * 512;

  f32x4 acc[4][6];
  const f32x4 zero = {0.f, 0.f, 0.f, 0.f};
  #pragma unroll
  for (int i = 0; i < 4; i++)
    #pragma unroll
    for (int j = 0; j < 6; j++) acc[i][j] = zero;

  for (int k0 = 0; k0 < CC; k0 += 32){
    async16(gX + k0, lX);
    async16(gW + k0,                  lW);
    async16(gW + k0 + (size_t)128*CC, lW + 4096);
    async16(gW + k0 + (size_t)256*CC, lW + 8192);
    __syncthreads();
    bf16x8 xf[4], wf[6];
    #pragma unroll
    for (int i = 0; i < 4; i++)
      xf[i] = *(const bf16x8*)&Xl[wn*64 + i*16 + l15][quad][0];
    #pragma unroll
    for (int j = 0; j < 6; j++)
      wf[j] = *(const bf16x8*)&Wl[wm*96 + j*16 + l15][quad][0];
    #pragma unroll
    for (int i = 0; i < 4; i++)
      #pragma unroll
      for (int j = 0; j < 6; j++)
        acc[i][j] = __builtin_amdgcn_mfma_f32_16x16x32_bf16(xf[i], wf[j], acc[i][j], 0, 0, 0);
    __syncthreads();
  }

  float bb[6];
  #pragma unroll
  for (int j = 0; j < 6; j++) bb[j] = bias[wm*96 + j*16 + l15];
  #pragma unroll
  for (int i = 0; i < 4; i++){
    int nb = n0 + wn*64 + i*16 + quad*4;
    #pragma unroll
    for (int r = 0; r < 4; r++){
      float* orow = xp + ((size_t)b * HWN + nb + r) * DD;
      #pragma unroll
      for (int j = 0; j < 6; j++)
        orow[wm*96 + j*16 + l15] = acc[i][j][r] + bb[j];
    }
  }
}

// ---------------- K2: per-token 1/max(||x_proj||,1e-12) ----------------
__global__ __launch_bounds__(256) void k2_rnorm(const float* __restrict__ xp,
                                                float* __restrict__ rn){
  int w = threadIdx.x >> 6, l = threadIdx.x & 63;
  int t = blockIdx.x * 4 + w;               // 0..32767
  const float* row = xp + (size_t)t * DD;
  float s = 0.f;
  #pragma unroll
  for (int i = 0; i < 6; i++){ float xv = row[l + 64*i]; s += xv*xv; }
  s = wave_sum(s);
  if (l == 0) rn[t] = 1.f / fmaxf(sqrtf(s), 1e-12f);
}

// ---------------- KXPT: emits BOTH bf16 views of xn = xp*rn:
//   xnb[b][n][d]  (same layout as xp; feeds k3's B operand)
//   XpT[b][d][n]  (transposed; feeds k5's B operand)
__global__ __launch_bounds__(256) void k_xpt(const float* __restrict__ xp,
                                             const float* __restrict__ rn,
                                             bf16* __restrict__ xpt,
                                             bf16* __restrict__ xnb){
  __shared__ float S[64][68];
  int b  = blockIdx.z;
  int d0 = blockIdx.y * 64;
  int n0 = blockIdx.x * 64;
  const float* xpb = xp + (size_t)b * HWN * DD;
  const float* rnb = rn + (size_t)b * HWN;
  int t = threadIdx.x;
  int rr = t >> 4, cc = (t & 15) * 4;
  #pragma unroll
  for (int it = 0; it < 4; it++){
    int row = rr + it*16;
    float sc = rnb[n0 + row];
    float4 v = *(const float4*)&xpb[(size_t)(n0 + row)*DD + d0 + cc];
    v.x *= sc; v.y *= sc; v.z *= sc; v.w *= sc;
    *(float4*)&S[row][cc] = v;
    bf16x4 o4;
    o4[0] = (bf16)v.x; o4[1] = (bf16)v.y; o4[2] = (bf16)v.z; o4[3] = (bf16)v.w;
    *(bf16x4*)&xnb[((size_t)b * HWN + n0 + row)*DD + d0 + cc] = o4;
  }
  __syncthreads();
  int d = t >> 2, c0 = (t & 3) * 16;   // lanes 0..3 cover 64 consecutive n of row d
  bf16* orow = xpt + (size_t)b * DD * HWN + (size_t)(d0 + d) * HWN + n0 + c0;
  bf16x8 o0, o1;
  #pragma unroll
  for (int jj = 0; jj < 8; jj++) o0[jj] = (bf16)S[c0 + jj][d];
  #pragma unroll
  for (int jj = 0; jj < 8; jj++) o1[jj] = (bf16)S[c0 + 8 + jj][d];
  *(bf16x8*)&orow[0] = o0;
  *(bf16x8*)&orow[8] = o1;
}

// ---------------- K3 (MFMA): Z[b][k][n] = (clusb[k][:] . xnb[n][:]) * EPSI ----------
// Grid (8 n-chunks x 32 b), 256 thr (4 waves, each 32 n). d-loop 12 steps of 32.
__global__ __launch_bounds__(256) void k3_scores(const bf16* __restrict__ clusb,
                                                 const bf16* __restrict__ xnb,
                                                 float* __restrict__ Z){
  __shared__ bf16 Al[64][4][8];    // 4 KB  clusters slab
  __shared__ bf16 Bl[128][4][8];   // 8 KB  xn slab
  int b = blockIdx.y, n0 = blockIdx.x * 128;
  const bf16* Xb = xnb + (size_t)b * HWN * DD;
  int t = threadIdx.x, wv = t >> 6, l = t & 63;
  int l15 = l & 15, quad = l >> 4;

  int rbase = wv*16 + (l >> 2);
  int kq8   = (l & 3) * 8;
  const bf16* gA = clusb + (size_t)rbase * DD + kq8;
  const bf16* gB = Xb + (size_t)(n0 + rbase) * DD + kq8;
  bf16* lA = &Al[0][0][0] + wv * 512;
  bf16* lB = &Bl[0][0][0] + wv * 512;

  f32x4 acc[4][2];
  const f32x4 zero = {0.f, 0.f, 0.f, 0.f};
  #pragma unroll
  for (int i = 0; i < 4; i++){ acc[i][0] = zero; acc[i][1] = zero; }

  for (int d0 = 0; d0 < DD; d0 += 32){
    async16(gA + d0, lA);
    async16(gB + d0,                 lB);
    async16(gB + d0 + (size_t)64*DD, lB + 2048);
    __syncthreads();
    bf16x8 af[4], bf[2];
    #pragma unroll
    for (int i = 0; i < 4; i++)
      af[i] = *(const bf16x8*)&Al[i*16 + l15][quad][0];
    #pragma unroll
    for (int j = 0; j < 2; j++)
      bf[j] = *(const bf16x8*)&Bl[wv*32 + j*16 + l15][quad][0];
    #pragma unroll
    for (int i = 0; i < 4; i++)
      #pragma unroll
      for (int j = 0; j < 2; j++)
        acc[i][j] = __builtin_amdgcn_mfma_f32_16x16x32_bf16(af[i], bf[j], acc[i][j], 0, 0, 0);
    __syncthreads();
  }
  #pragma unroll
  for (int i = 0; i < 4; i++){
    #pragma unroll
    for (int j = 0; j < 2; j++){
      int n = n0 + wv*32 + j*16 + l15;
      #pragma unroll
      for (int r = 0; r < 4; r++){
        int k = i*16 + quad*4 + r;
        Z[((size_t)b*KK + k)*HWN + n] = acc[i][j][r] * EPSI;
      }
    }
  }
}

// ---------------- K4: Sinkhorn, one 1024-thr block per batch, E=exp(Z-rmax) in f16 LDS
// u[r] = NORMC - rmax[r] - log(sum_n E[r][n]*ev[n]);  eu[r] = exp(NORMC)/sum  (exact)
// v[c] = NORMC - log(sum_m E[m][c]*eu[m]);            ev[c] = exp(v[c])
// NOTE: v reaches ~+12 here (asymmetric marginals 64 vs 1024), so ev MUST be fp32 —
// f16 ev (max 65504 = e^11.09) overflowed to Inf in R3 and cascaded to NaN.
// E in (0,1] is always f16-safe. ~145 KB LDS (gfx950: 160 KB/CU).
__global__ __launch_bounds__(1024) void k4_sinkhorn(const float* __restrict__ Z,
                                                    float* __restrict__ U,
                                                    float* __restrict__ V){
  __shared__ f16  E[64][1024];    // 128 KB
  __shared__ float evf[1024];     // exp(v), fp32 (overflow-safe)
  __shared__ float eu[64];
  __shared__ float rmax[64];
  __shared__ float u_l[64];
  __shared__ float v_l[1024];
  __shared__ float sp[2][1024];   // v-phase partials per column (two row-halves)
  int b = blockIdx.x;
  const float* Zb = Z + (size_t)b * KK * HWN;
  int t = threadIdx.x, w = t >> 6, l = t & 63;

  // ---- stage: wave w owns rows 4w..4w+3; compute rowmax, E = f16(exp(Z - rmax))
  #pragma unroll
  for (int rr = 0; rr < 4; rr++){
    int r = w*4 + rr;
    float4 z[4];
    float mx = -INFINITY;
    #pragma unroll
    for (int j = 0; j < 4; j++){
      z[j] = *(const float4*)&Zb[(size_t)r*HWN + 4*l + 256*j];
      mx = fmaxf(mx, fmaxf(fmaxf(z[j].x, z[j].y), fmaxf(z[j].z, z[j].w)));
    }
    mx = wave_max(mx);
    if (l == 0) rmax[r] = mx;
    #pragma unroll
    for (int j = 0; j < 4; j++){
      f16x4 e4;
      e4[0] = (f16)__expf(z[j].x - mx); e4[1] = (f16)__expf(z[j].y - mx);
      e4[2] = (f16)__expf(z[j].z - mx); e4[3] = (f16)__expf(z[j].w - mx);
      *(f16x4*)&E[r][4*l + 256*j] = e4;
    }
  }
  evf[t] = 1.f;
  v_l[t] = 0.f;
  __syncthreads();

  for (int it = 0; it < NITERS; it++){
    // ---- u-phase: wave w -> rows 4w..4w+3; lane l covers col-pairs p = l+64j
    float evx[16];
    #pragma unroll
    for (int j = 0; j < 8; j++){
      float2 e2 = *(const float2*)&evf[2*(l + 64*j)];
      evx[2*j] = e2.x; evx[2*j+1] = e2.y;
    }
    float us[4];
    #pragma unroll
    for (int rr = 0; rr < 4; rr++){
      int r = w*4 + rr;
      float s = 0.f;
      #pragma unroll
      for (int j = 0; j < 8; j++){
        f16x2 e2 = *(const f16x2*)&E[r][2*(l + 64*j)];
        s = fmaf((float)e2[0], evx[2*j],   s);
        s = fmaf((float)e2[1], evx[2*j+1], s);
      }
      us[rr] = wave_sum(s);
    }
    if (l == 0){
      #pragma unroll
      for (int rr = 0; rr < 4; rr++){
        int r = w*4 + rr;
        u_l[r] = NORMC - rmax[r] - __logf(us[rr]);
        eu[r]  = __expf(NORMC) / us[rr];      // = exp(u+rmax), no transcendental
      }
    }
    __syncthreads();
    // ---- v-phase: thread t -> col pair p = t&511, row half h = t>>9
    {
      int p = t & 511, h = t >> 9;
      float sx = 0.f, sy = 0.f;
      #pragma unroll
      for (int mq = 0; mq < 8; mq++){
        float4 eu4 = *(const float4*)&eu[h*32 + mq*4];
        const float euv[4] = {eu4.x, eu4.y, eu4.z, eu4.w};
        #pragma unroll
        for (int i = 0; i < 4; i++){
          f16x2 e2 = *(const f16x2*)&E[h*32 + mq*4 + i][2*p];
          sx = fmaf((float)e2[0], euv[i], sx);
          sy = fmaf((float)e2[1], euv[i], sy);
        }
      }
      float2 o; o.x = sx; o.y = sy;
      *(float2*)&sp[h][2*p] = o;
    }
    __syncthreads();
    if (t < 512){
      int p = t;
      float2 a = *(const float2*)&sp[0][2*p];
      float2 c = *(const float2*)&sp[1][2*p];
      float vx = NORMC - __logf(a.x + c.x);
      float vy = NORMC - __logf(a.y + c.y);
      v_l[2*p]   = vx;
      v_l[2*p+1] = vy;
      float2 ee; ee.x = __expf(vx); ee.y = __expf(vy);
      *(float2*)&evf[2*p] = ee;
    }
    __syncthreads();
  }
  V[b*HWN + t] = v_l[t];
  if (t < 64) U[b*KK + t] = u_l[t];
}

// ---------------- K5 (MFMA, split-K over n): out[b][k][d] += sum_n E'[k][n]*XpT[d][n]
// E'[k][n] = exp(Z+u+v-NORMC) in bf16 (rn already folded into XpT).
// Grid (8 chunks x 32 b) = 256 blocks; 4 n-steps of 32 per block; atomic partials.
__global__ __launch_bounds__(256) void k5_mfma(const float* __restrict__ Z,
                                               const float* __restrict__ U,
                                               const float* __restrict__ V,
                                               const bf16* __restrict__ XpT,
                                               float* __restrict__ out){
  __shared__ bf16 El[64][40];     // 5 KB   [k][n-step]
  __shared__ bf16 Xl[384][40];    // 30 KB  [d][n-step]
  int b  = blockIdx.y;
  int nsb = blockIdx.x * 128;     // n-chunk base
  const float* Zb = Z + (size_t)b * KK * HWN;
  const bf16*  Xb = XpT + (size_t)b * DD * HWN;
  const float* Vb = V + (size_t)b * HWN;
  int t = threadIdx.x, wv = t >> 6, l = t & 63;
  int l15 = l & 15, quad = l >> 4;
  int er = t >> 2, ec0 = (t & 3) * 8;         // E-stage: row, col-offset (fixed/thread)
  float ur = U[b*KK + er];

  f32x4 acc[4][6];
  const f32x4 zero = {0.f, 0.f, 0.f, 0.f};
  #pragma unroll
  for (int i = 0; i < 4; i++)
    #pragma unroll
    for (int j = 0; j < 6; j++) acc[i][j] = zero;

  for (int st = 0; st < 4; st++){
    int n0 = nsb + st*32;
    // ---- stage E' = bf16(exp(Z + u + v - NORMC)) : 64x32
    {
      float4 z0 = *(const float4*)&Zb[(size_t)er*HWN + n0 + ec0];
      float4 z1 = *(const float4*)&Zb[(size_t)er*HWN + n0 + ec0 + 4];
      float4 v0 = *(const float4*)&Vb[n0 + ec0];
      float4 v1 = *(const float4*)&Vb[n0 + ec0 + 4];
      bf16x8 e;
      e[0] = (bf16)__expf(z0.x + ur + v0.x - NORMC);
      e[1] = (bf16)__expf(z0.y + ur + v0.y - NORMC);
      e[2] = (bf16)__expf(z0.z + ur + v0.z - NORMC);
      e[3] = (bf16)__expf(z0.w + ur + v0.w - NORMC);
      e[4] = (bf16)__expf(z1.x + ur + v1.x - NORMC);
      e[5] = (bf16)__expf(z1.y + ur + v1.y - NORMC);
      e[6] = (bf16)__expf(z1.z + ur + v1.z - NORMC);
      e[7] = (bf16)__expf(z1.w + ur + v1.w - NORMC);
      *(bf16x8*)&El[er][ec0] = e;
    }
    // ---- stage XpT slab: 384 rows x 32 n (bf16, pure copy); 6 x 16B per thread
    #pragma unroll
    for (int ii = 0; ii < 6; ii++){
      int chunk = t + 256*ii;
      int d = chunk >> 2, cb = (chunk & 3) * 8;
      bf16x8 xv = *(const bf16x8*)&Xb[(size_t)d*HWN + n0 + cb];
      *(bf16x8*)&Xl[d][cb] = xv;
    }
    __syncthreads();
    bf16x8 af[4], bfr[6];
    #pragma unroll
    for (int i = 0; i < 4; i++)
      af[i] = *(const bf16x8*)&El[i*16 + l15][quad*8];
    #pragma unroll
    for (int j = 0; j < 6; j++)
      bfr[j] = *(const bf16x8*)&Xl[wv*96 + j*16 + l15][quad*8];
    #pragma unroll
    for (int i = 0; i < 4; i++)
      #pragma unroll
      for (int j = 0; j < 6; j++)
        acc[i][j] = __builtin_amdgcn_mfma_f32_16x16x32_bf16(af[i], bfr[j], acc[i][j], 0, 0, 0);
    __syncthreads();
  }

  // ---- epilogue: atomic partial add (out zeroed by hipMemsetAsync)
  float* ob = out + (size_t)b * KK * DD;
  #pragma unroll
  for (int i = 0; i < 4; i++){
    int kbase = i*16 + quad*4;
    #pragma unroll
    for (int j = 0; j < 6; j++){
      int d = wv*96 + j*16 + l15;
      #pragma unroll
      for (int r = 0; r < 4; r++)
        unsafeAtomicAdd(&ob[(size_t)(kbase + r)*DD + d], acc[i][j][r]);
    }
  }
}

extern "C" void kernel_launch(void* const* d_in, const int* in_sizes, int n_in,
                              void* d_out, int out_size, void* d_ws, size_t ws_size,
                              hipStream_t stream) {
  const float* x      = (const float*)d_in[0];   // [32,768,32,32]
  const float* conv_w = (const float*)d_in[1];   // [384,768]
  const float* conv_b = (const float*)d_in[2];   // [384]
  const float* vcode  = (const float*)d_in[3];   // [64,384]
  float* out = (float*)d_out;
  float* vt_out = out;                 // [32,64,384]  = 786432
  float* xp_out = out + 786432;        // [32,1024,384]

  bf16* Xt    = (bf16*)d_ws;                         // 25,165,824 bf16 (50.3 MB)
  bf16* Wb    = Xt + (size_t)BB * HWN * CC;          // 294,912 bf16
  bf16* clusb = Wb + (size_t)DD * CC;                // 24,576 bf16
  float* Zbuf = (float*)(clusb + 24576);             // 2,097,152 f32
  float* Ubuf = Zbuf + 2097152;                      // 2,048
  float* Vbuf = Ubuf + 2048;                         // 32,768
  float* Rn   = Vbuf + 32768;                        // 32,768
  bf16* xnb   = (bf16*)(Rn + 32768);                 // 12,582,912 bf16 (25.2 MB)
  bf16* XpT   = Xt;   // alias: Xt dead after k_gemm; XpT = xn^T bf16 [32][384][1024]

  hipMemsetAsync(vt_out, 0, (size_t)786432 * sizeof(float), stream);
  k0_clusters<<<16, 256, 0, stream>>>(vcode, clusb);
  k_wconv<<<288, 256, 0, stream>>>(conv_w, Wb);
  k_xt<<<dim3(16, 12, 32), 256, 0, stream>>>(x, Xt);
  k_gemm<<<dim3(8, 32), 512, 0, stream>>>(Wb, Xt, conv_b, xp_out);
  k2_rnorm<<<8192, 256, 0, stream>>>(xp_out, Rn);
  k_xpt<<<dim3(16, 6, 32), 256, 0, stream>>>(xp_out, Rn, XpT, xnb);
  k3_scores<<<dim3(8, 32), 256, 0, stream>>>(clusb, xnb, Zbuf);
  k4_sinkhorn<<<32, 1024, 0, stream>>>(Zbuf, Ubuf, Vbuf);
  k5_mfma<<<dim3(8, 32), 256, 0, stream>>>(Zbuf, Ubuf, Vbuf, XpT, vt_out);
}

// Round 4
// 295.903 us; speedup vs baseline: 1.2082x; 1.0481x over previous
//
#include <hip/hip_runtime.h>
#include <math.h>

#define BB 32
#define CC 768
#define HWN 1024
#define DD 384
#define KK 64
#define EPSI 20.0f            // 1/eps
#define NORMC (-6.9920964f)   // -log(1088)
#define NITERS 10

typedef __bf16 bf16;
typedef bf16 bf16x8 __attribute__((ext_vector_type(8)));
typedef bf16 bf16x4 __attribute__((ext_vector_type(4)));
typedef float f32x4 __attribute__((ext_vector_type(4)));
typedef _Float16 f16;
typedef f16 f16x2 __attribute__((ext_vector_type(2)));
typedef f16 f16x4 __attribute__((ext_vector_type(4)));

__device__ __forceinline__ float wave_sum(float v){
  #pragma unroll
  for (int off = 32; off; off >>= 1) v += __shfl_xor(v, off, 64);
  return v;
}
__device__ __forceinline__ float wave_max(float v){
  #pragma unroll
  for (int off = 32; off; off >>= 1) v = fmaxf(v, __shfl_xor(v, off, 64));
  return v;
}

__device__ __forceinline__ void async16(const bf16* g, bf16* l){
  __builtin_amdgcn_global_load_lds((const __attribute__((address_space(1))) unsigned int*)g,
                                   (__attribute__((address_space(3))) unsigned int*)l,
                                   16, 0, 0);
}

// ---------------- K0: normalize codebook rows v[64][384] -> clusb (bf16) ------------
__global__ __launch_bounds__(256) void k0_clusters(const float* __restrict__ vin,
                                                   bf16* __restrict__ clusb){
  int w = threadIdx.x >> 6, l = threadIdx.x & 63;
  int k = blockIdx.x * 4 + w;               // 16 blocks * 4 waves = 64 rows
  float s = 0.f;
  #pragma unroll
  for (int i = 0; i < 6; i++){ float x = vin[k*DD + l + 64*i]; s += x*x; }
  s = wave_sum(s);
  float scale = 1.f / fmaxf(sqrtf(s), 1e-12f);
  #pragma unroll
  for (int i = 0; i < 6; i++) clusb[k*DD + l + 64*i] = (bf16)(vin[k*DD + l + 64*i] * scale);
}

// ---------------- KW: convert conv_w fp32[384][768] -> bf16 ----------------
__global__ __launch_bounds__(256) void k_wconv(const float* __restrict__ w,
                                               bf16* __restrict__ wb){
  int i = (blockIdx.x * 256 + threadIdx.x) * 4;
  float4 v = *(const float4*)&w[i];
  bf16x4 o;
  o[0] = (bf16)v.x; o[1] = (bf16)v.y; o[2] = (bf16)v.z; o[3] = (bf16)v.w;
  *(bf16x4*)&wb[i] = o;
}

// ---------------- K1: fused GEMM front-end.
// xp[b][n][m] = sum_c X[b][c][n] * W[m][c] + bias[m]   (X transposed on the fly in LDS)
// also: rn[n] = 1/max(||xp row||,1e-12) computed in-block; xnb[b][n][m] = bf16(xp*rn).
// Grid (8 n-chunks x 32 b) = 256 blocks, 512 thr (8 waves = 2n x 4m).
// X staging: thread loads float4 of rows (c2,c2+1); writes float2 (c2,c2+1) into
// Xf[n][36] with 8-float XOR block swizzle s(n)=((n>>2)^(n>>4))&3 (blk' = blk ^ s).
// Frag reads: 2x float4 at blk = quad^s -> cvt to bf16x8. 2-way banks (free).
__global__ __launch_bounds__(512) void k_gemm(const bf16* __restrict__ Wb,
                                              const float* __restrict__ X,
                                              const float* __restrict__ bias,
                                              float* __restrict__ xp,
                                              bf16* __restrict__ xnb){
  __shared__ bf16  Wl[384][4][8];     // 24 KB
  __shared__ float Xf[128 * 36];      // 18 KB  [n][36] fp32, swizzled 8-blocks
  __shared__ float part[4][128];      // 2 KB   per-wm row sumsq partials
  __shared__ float rn_l[128];
  int b  = blockIdx.y;
  int n0 = blockIdx.x * 128;
  int t = threadIdx.x, wv = t >> 6, l = t & 63;
  int l15 = l & 15, quad = l >> 4;
  int wn = wv >> 2, wm = wv & 3;
  const float* Xg = X + (size_t)b * CC * HWN;

  // W staging (unchanged pattern): wave-linear async16 into [row][kq][8]
  int rbase = wv*16 + (l >> 2);
  int kq8   = (l & 3) * 8;
  const bf16* gW = Wb + (size_t)rbase * CC + kq8;
  bf16* lW = &Wl[0][0][0] + wv * 512;

  // X staging assignment: q = t&31 -> n4 = 4q; h = t>>5 -> c2 = 2h
  int q = t & 31, h = t >> 5;
  int n4 = q * 4, c2 = h * 2;
  int sthr = (q ^ (q >> 2)) & 3;                 // s(n) for n = 4q+k (k<4)
  int coff = (((c2 >> 3) ^ sthr) << 3) + (c2 & 7);

  f32x4 acc[4][6];
  const f32x4 zero = {0.f, 0.f, 0.f, 0.f};
  #pragma unroll
  for (int i = 0; i < 4; i++)
    #pragma unroll
    for (int j = 0; j < 6; j++) acc[i][j] = zero;

  // frag-read swizzle constants
  int a_ = l15 >> 2;

  for (int c0 = 0; c0 < CC; c0 += 32){
    // X: load 2 rows x 4 n, scatter-transpose into Xf
    const float* xr = Xg + (size_t)(c0 + c2) * HWN + n0 + n4;
    float4 v0 = *(const float4*)xr;
    float4 v1 = *(const float4*)(xr + HWN);
    {
      float2 w0; w0.x = v0.x; w0.y = v1.x;
      float2 w1; w1.x = v0.y; w1.y = v1.y;
      float2 w2; w2.x = v0.z; w2.y = v1.z;
      float2 w3; w3.x = v0.w; w3.y = v1.w;
      *(float2*)&Xf[(n4+0)*36 + coff] = w0;
      *(float2*)&Xf[(n4+1)*36 + coff] = w1;
      *(float2*)&Xf[(n4+2)*36 + coff] = w2;
      *(float2*)&Xf[(n4+3)*36 + coff] = w3;
    }
    // W: async16 x3 (128-row groups)
    async16(gW + c0,                  lW);
    async16(gW + c0 + (size_t)128*CC, lW + 4096);
    async16(gW + c0 + (size_t)256*CC, lW + 8192);
    __syncthreads();

    bf16x8 xf[4], wf[6];
    #pragma unroll
    for (int i = 0; i < 4; i++){
      int nloc = wn*64 + i*16 + l15;
      int s = (a_ ^ (wn*4 + i)) & 3;
      int blk = quad ^ s;
      const float4 f0 = *(const float4*)&Xf[nloc*36 + blk*8];
      const float4 f1 = *(const float4*)&Xf[nloc*36 + blk*8 + 4];
      bf16x8 xv;
      xv[0] = (bf16)f0.x; xv[1] = (bf16)f0.y; xv[2] = (bf16)f0.z; xv[3] = (bf16)f0.w;
      xv[4] = (bf16)f1.x; xv[5] = (bf16)f1.y; xv[6] = (bf16)f1.z; xv[7] = (bf16)f1.w;
      xf[i] = xv;
    }
    #pragma unroll
    for (int j = 0; j < 6; j++)
      wf[j] = *(const bf16x8*)&Wl[wm*96 + j*16 + l15][quad][0];
    #pragma unroll
    for (int i = 0; i < 4; i++)
      #pragma unroll
      for (int j = 0; j < 6; j++)
        acc[i][j] = __builtin_amdgcn_mfma_f32_16x16x32_bf16(xf[i], wf[j], acc[i][j], 0, 0, 0);
    __syncthreads();
  }

  float bb[6];
  #pragma unroll
  for (int j = 0; j < 6; j++) bb[j] = bias[wm*96 + j*16 + l15];

  // ---- rnorm: per-row sumsq (j-sum, l15-reduce, cross-wm via LDS)
  #pragma unroll
  for (int i = 0; i < 4; i++){
    #pragma unroll
    for (int r = 0; r < 4; r++){
      float s = 0.f;
      #pragma unroll
      for (int j = 0; j < 6; j++){ float v = acc[i][j][r] + bb[j]; s = fmaf(v, v, s); }
      s += __shfl_xor(s, 1, 64); s += __shfl_xor(s, 2, 64);
      s += __shfl_xor(s, 4, 64); s += __shfl_xor(s, 8, 64);
      if (l15 == 0) part[wm][wn*64 + i*16 + quad*4 + r] = s;
    }
  }
  __syncthreads();
  if (t < 128){
    float tot = part[0][t] + part[1][t] + part[2][t] + part[3][t];
    rn_l[t] = 1.f / fmaxf(sqrtf(tot), 1e-12f);
  }
  __syncthreads();

  // ---- write xp fp32 + xnb bf16
  #pragma unroll
  for (int i = 0; i < 4; i++){
    #pragma unroll
    for (int r = 0; r < 4; r++){
      int nloc = wn*64 + i*16 + quad*4 + r;
      float rv = rn_l[nloc];
      float* orow = xp  + ((size_t)b * HWN + n0 + nloc) * DD;
      bf16*  xrow = xnb + ((size_t)b * HWN + n0 + nloc) * DD;
      #pragma unroll
      for (int j = 0; j < 6; j++){
        int m = wm*96 + j*16 + l15;
        float val = acc[i][j][r] + bb[j];
        orow[m] = val;
        xrow[m] = (bf16)(val * rv);
      }
    }
  }
}

// ---------------- KXPT2: bf16 transpose  XpT[b][d][n] = xnb[b][n][d] ----------------
__global__ __launch_bounds__(256) void k_xpt2(const bf16* __restrict__ xnb,
                                              bf16* __restrict__ xpt){
  __shared__ bf16 S[64][72];   // pad 8 bf16 (row 144B)
  int b  = blockIdx.z;
  int d0 = blockIdx.y * 64;
  int n0 = blockIdx.x * 64;
  const bf16* src = xnb + ((size_t)b * HWN + n0) * DD + d0;
  int t = threadIdx.x;
  int r = t >> 3, c8 = (t & 7) * 8;
  #pragma unroll
  for (int it = 0; it < 2; it++){
    bf16x8 v = *(const bf16x8*)&src[(size_t)(r + it*32) * DD + c8];
    *(bf16x8*)&S[r + it*32][c8] = v;
  }
  __syncthreads();
  int d = t >> 2, c0 = (t & 3) * 16;
  bf16* orow = xpt + ((size_t)b * DD + d0 + d) * HWN + n0 + c0;
  bf16x8 o0, o1;
  #pragma unroll
  for (int jj = 0; jj < 8; jj++) o0[jj] = S[c0 + jj][d];
  #pragma unroll
  for (int jj = 0; jj < 8; jj++) o1[jj] = S[c0 + 8 + jj][d];
  *(bf16x8*)&orow[0] = o0;
  *(bf16x8*)&orow[8] = o1;
}

// ---------------- K3 (MFMA): Z[b][k][n] = (clusb[k][:] . xnb[n][:]) * EPSI ----------
__global__ __launch_bounds__(256) void k3_scores(const bf16* __restrict__ clusb,
                                                 const bf16* __restrict__ xnb,
                                                 float* __restrict__ Z){
  __shared__ bf16 Al[64][4][8];    // 4 KB  clusters slab
  __shared__ bf16 Bl[128][4][8];   // 8 KB  xn slab
  int b = blockIdx.y, n0 = blockIdx.x * 128;
  const bf16* Xb = xnb + (size_t)b * HWN * DD;
  int t = threadIdx.x, wv = t >> 6, l = t & 63;
  int l15 = l & 15, quad = l >> 4;

  int rbase = wv*16 + (l >> 2);
  int kq8   = (l & 3) * 8;
  const bf16* gA = clusb + (size_t)rbase * DD + kq8;
  const bf16* gB = Xb + (size_t)(n0 + rbase) * DD + kq8;
  bf16* lA = &Al[0][0][0] + wv * 512;
  bf16* lB = &Bl[0][0][0] + wv * 512;

  f32x4 acc[4][2];
  const f32x4 zero = {0.f, 0.f, 0.f, 0.f};
  #pragma unroll
  for (int i = 0; i < 4; i++){ acc[i][0] = zero; acc[i][1] = zero; }

  for (int d0 = 0; d0 < DD; d0 += 32){
    async16(gA + d0, lA);
    async16(gB + d0,                 lB);
    async16(gB + d0 + (size_t)64*DD, lB + 2048);
    __syncthreads();
    bf16x8 af[4], bf[2];
    #pragma unroll
    for (int i = 0; i < 4; i++)
      af[i] = *(const bf16x8*)&Al[i*16 + l15][quad][0];
    #pragma unroll
    for (int j = 0; j < 2; j++)
      bf[j] = *(const bf16x8*)&Bl[wv*32 + j*16 + l15][quad][0];
    #pragma unroll
    for (int i = 0; i < 4; i++)
      #pragma unroll
      for (int j = 0; j < 2; j++)
        acc[i][j] = __builtin_amdgcn_mfma_f32_16x16x32_bf16(af[i], bf[j], acc[i][j], 0, 0, 0);
    __syncthreads();
  }
  #pragma unroll
  for (int i = 0; i < 4; i++){
    #pragma unroll
    for (int j = 0; j < 2; j++){
      int n = n0 + wv*32 + j*16 + l15;
      #pragma unroll
      for (int r = 0; r < 4; r++){
        int k = i*16 + quad*4 + r;
        Z[((size_t)b*KK + k)*HWN + n] = acc[i][j][r] * EPSI;
      }
    }
  }
}

// ---------------- K4: Sinkhorn, one 1024-thr block per batch, E=exp(Z-rmax) in f16 LDS
// u[r] = NORMC - rmax[r] - log(sum_n E[r][n]*ev[n]);  eu[r] = exp(NORMC)/sum  (exact)
// v[c] = NORMC - log(sum_m E[m][c]*eu[m]);            ev[c] = exp(v[c])
// NOTE: v reaches ~+12 (asymmetric marginals 64 vs 1024) -> ev MUST be fp32.
// E in (0,1] is always f16-safe. ~145 KB LDS (gfx950: 160 KB/CU).
__global__ __launch_bounds__(1024) void k4_sinkhorn(const float* __restrict__ Z,
                                                    float* __restrict__ U,
                                                    float* __restrict__ V){
  __shared__ f16  E[64][1024];    // 128 KB
  __shared__ float evf[1024];     // exp(v), fp32 (overflow-safe)
  __shared__ float eu[64];
  __shared__ float rmax[64];
  __shared__ float u_l[64];
  __shared__ float v_l[1024];
  __shared__ float sp[2][1024];   // v-phase partials per column (two row-halves)
  int b = blockIdx.x;
  const float* Zb = Z + (size_t)b * KK * HWN;
  int t = threadIdx.x, w = t >> 6, l = t & 63;

  #pragma unroll
  for (int rr = 0; rr < 4; rr++){
    int r = w*4 + rr;
    float4 z[4];
    float mx = -INFINITY;
    #pragma unroll
    for (int j = 0; j < 4; j++){
      z[j] = *(const float4*)&Zb[(size_t)r*HWN + 4*l + 256*j];
      mx = fmaxf(mx, fmaxf(fmaxf(z[j].x, z[j].y), fmaxf(z[j].z, z[j].w)));
    }
    mx = wave_max(mx);
    if (l == 0) rmax[r] = mx;
    #pragma unroll
    for (int j = 0; j < 4; j++){
      f16x4 e4;
      e4[0] = (f16)__expf(z[j].x - mx); e4[1] = (f16)__expf(z[j].y - mx);
      e4[2] = (f16)__expf(z[j].z - mx); e4[3] = (f16)__expf(z[j].w - mx);
      *(f16x4*)&E[r][4*l + 256*j] = e4;
    }
  }
  evf[t] = 1.f;
  v_l[t] = 0.f;
  __syncthreads();

  for (int it = 0; it < NITERS; it++){
    float evx[16];
    #pragma unroll
    for (int j = 0; j < 8; j++){
      float2 e2 = *(const float2*)&evf[2*(l + 64*j)];
      evx[2*j] = e2.x; evx[2*j+1] = e2.y;
    }
    float us[4];
    #pragma unroll
    for (int rr = 0; rr < 4; rr++){
      int r = w*4 + rr;
      float s = 0.f;
      #pragma unroll
      for (int j = 0; j < 8; j++){
        f16x2 e2 = *(const f16x2*)&E[r][2*(l + 64*j)];
        s = fmaf((float)e2[0], evx[2*j],   s);
        s = fmaf((float)e2[1], evx[2*j+1], s);
      }
      us[rr] = wave_sum(s);
    }
    if (l == 0){
      #pragma unroll
      for (int rr = 0; rr < 4; rr++){
        int r = w*4 + rr;
        u_l[r] = NORMC - rmax[r] - __logf(us[rr]);
        eu[r]  = __expf(NORMC) / us[rr];
      }
    }
    __syncthreads();
    {
      int p = t & 511, h = t >> 9;
      float sx = 0.f, sy = 0.f;
      #pragma unroll
      for (int mq = 0; mq < 8; mq++){
        float4 eu4 = *(const float4*)&eu[h*32 + mq*4];
        const float euv[4] = {eu4.x, eu4.y, eu4.z, eu4.w};
        #pragma unroll
        for (int i = 0; i < 4; i++){
          f16x2 e2 = *(const f16x2*)&E[h*32 + mq*4 + i][2*p];
          sx = fmaf((float)e2[0], euv[i], sx);
          sy = fmaf((float)e2[1], euv[i], sy);
        }
      }
      float2 o; o.x = sx; o.y = sy;
      *(float2*)&sp[h][2*p] = o;
    }
    __syncthreads();
    if (t < 512){
      int p = t;
      float2 a = *(const float2*)&sp[0][2*p];
      float2 c = *(const float2*)&sp[1][2*p];
      float vx = NORMC - __logf(a.x + c.x);
      float vy = NORMC - __logf(a.y + c.y);
      v_l[2*p]   = vx;
      v_l[2*p+1] = vy;
      float2 ee; ee.x = __expf(vx); ee.y = __expf(vy);
      *(float2*)&evf[2*p] = ee;
    }
    __syncthreads();
  }
  V[b*HWN + t] = v_l[t];
  if (t < 64) U[b*KK + t] = u_l[t];
}

// ---------------- K5 (MFMA, split-K over n): out[b][k][d] += sum_n E'[k][n]*XpT[d][n]
// E'[k][n] = exp(Z+u+v-NORMC) in bf16 (rn already folded into XpT).
// Grid (8 chunks x 32 b) = 256 blocks; 4 n-steps of 32 per block; atomic partials.
__global__ __launch_bounds__(256) void k5_mfma(const float* __restrict__ Z,
                                               const float* __restrict__ U,
                                               const float* __restrict__ V,
                                               const bf16* __restrict__ XpT,
                                               float* __restrict__ out){
  __shared__ bf16 El[64][40];     // 5 KB   [k][n-step]
  __shared__ bf16 Xl[384][40];    // 30 KB  [d][n-step]
  int b  = blockIdx.y;
  int nsb = blockIdx.x * 128;     // n-chunk base
  const float* Zb = Z + (size_t)b * KK * HWN;
  const bf16*  Xb = XpT + (size_t)b * DD * HWN;
  const float* Vb = V + (size_t)b * HWN;
  int t = threadIdx.x, wv = t >> 6, l = t & 63;
  int l15 = l & 15, quad = l >> 4;
  int er = t >> 2, ec0 = (t & 3) * 8;
  float ur = U[b*KK + er];

  f32x4 acc[4][6];
  const f32x4 zero = {0.f, 0.f, 0.f, 0.f};
  #pragma unroll
  for (int i = 0; i < 4; i++)
    #pragma unroll
    for (int j = 0; j < 6; j++) acc[i][j] = zero;

  for (int st = 0; st < 4; st++){
    int n0 = nsb + st*32;
    {
      float4 z0 = *(const float4*)&Zb[(size_t)er*HWN + n0 + ec0];
      float4 z1 = *(const float4*)&Zb[(size_t)er*HWN + n0 + ec0 + 4];
      float4 v0 = *(const float4*)&Vb[n0 + ec0];
      float4 v1 = *(const float4*)&Vb[n0 + ec0 + 4];
      bf16x8 e;
      e[0] = (bf16)__expf(z0.x + ur + v0.x - NORMC);
      e[1] = (bf16)__expf(z0.y + ur + v0.y - NORMC);
      e[2] = (bf16)__expf(z0.z + ur + v0.z - NORMC);
      e[3] = (bf16)__expf(z0.w + ur + v0.w - NORMC);
      e[4] = (bf16)__expf(z1.x + ur + v1.x - NORMC);
      e[5] = (bf16)__expf(z1.y + ur + v1.y - NORMC);
      e[6] = (bf16)__expf(z1.z + ur + v1.z - NORMC);
      e[7] = (bf16)__expf(z1.w + ur + v1.w - NORMC);
      *(bf16x8*)&El[er][ec0] = e;
    }
    #pragma unroll
    for (int ii = 0; ii < 6; ii++){
      int chunk = t + 256*ii;
      int d = chunk >> 2, cb = (chunk & 3) * 8;
      bf16x8 xv = *(const bf16x8*)&Xb[(size_t)d*HWN + n0 + cb];
      *(bf16x8*)&Xl[d][cb] = xv;
    }
    __syncthreads();
    bf16x8 af[4], bfr[6];
    #pragma unroll
    for (int i = 0; i < 4; i++)
      af[i] = *(const bf16x8*)&El[i*16 + l15][quad*8];
    #pragma unroll
    for (int j = 0; j < 6; j++)
      bfr[j] = *(const bf16x8*)&Xl[wv*96 + j*16 + l15][quad*8];
    #pragma unroll
    for (int i = 0; i < 4; i++)
      #pragma unroll
      for (int j = 0; j < 6; j++)
        acc[i][j] = __builtin_amdgcn_mfma_f32_16x16x32_bf16(af[i], bfr[j], acc[i][j], 0, 0, 0);
    __syncthreads();
  }

  float* ob = out + (size_t)b * KK * DD;
  #pragma unroll
  for (int i = 0; i < 4; i++){
    int kbase = i*16 + quad*4;
    #pragma unroll
    for (int j = 0; j < 6; j++){
      int d = wv*96 + j*16 + l15;
      #pragma unroll
      for (int r = 0; r < 4; r++)
        unsafeAtomicAdd(&ob[(size_t)(kbase + r)*DD + d], acc[i][j][r]);
    }
  }
}

extern "C" void kernel_launch(void* const* d_in, const int* in_sizes, int n_in,
                              void* d_out, int out_size, void* d_ws, size_t ws_size,
                              hipStream_t stream) {
  const float* x      = (const float*)d_in[0];   // [32,768,32,32]
  const float* conv_w = (const float*)d_in[1];   // [384,768]
  const float* conv_b = (const float*)d_in[2];   // [384]
  const float* vcode  = (const float*)d_in[3];   // [64,384]
  float* out = (float*)d_out;
  float* vt_out = out;                 // [32,64,384]  = 786432
  float* xp_out = out + 786432;        // [32,1024,384]

  bf16* xnb   = (bf16*)d_ws;                         // 12,582,912 bf16 (25.2 MB)
  bf16* XpT   = xnb + (size_t)BB * HWN * DD;         // 12,582,912 bf16 (25.2 MB)
  bf16* Wb    = XpT + (size_t)BB * HWN * DD;         // 294,912 bf16
  bf16* clusb = Wb + (size_t)DD * CC;                // 24,576 bf16
  float* Zbuf = (float*)(clusb + 24576);             // 2,097,152 f32
  float* Ubuf = Zbuf + 2097152;                      // 2,048
  float* Vbuf = Ubuf + 2048;                         // 32,768

  hipMemsetAsync(vt_out, 0, (size_t)786432 * sizeof(float), stream);
  k0_clusters<<<16, 256, 0, stream>>>(vcode, clusb);
  k_wconv<<<288, 256, 0, stream>>>(conv_w, Wb);
  k_gemm<<<dim3(8, 32), 512, 0, stream>>>(Wb, x, conv_b, xp_out, xnb);
  k_xpt2<<<dim3(16, 6, 32), 256, 0, stream>>>(xnb, XpT);
  k3_scores<<<dim3(8, 32), 256, 0, stream>>>(clusb, xnb, Zbuf);
  k4_sinkhorn<<<32, 1024, 0, stream>>>(Zbuf, Ubuf, Vbuf);
  k5_mfma<<<dim3(8, 32), 256, 0, stream>>>(Zbuf, Ubuf, Vbuf, XpT, vt_out);
}

// Round 5
// 273.947 us; speedup vs baseline: 1.3050x; 1.0801x over previous
//
#include <hip/hip_runtime.h>
#include <math.h>

#define BB 32
#define CC 768
#define HWN 1024
#define DD 384
#define KK 64
#define EPSI 20.0f            // 1/eps
#define NORMC (-6.9920964f)   // -log(1088)
#define NITERS 10

typedef __bf16 bf16;
typedef bf16 bf16x8 __attribute__((ext_vector_type(8)));
typedef bf16 bf16x4 __attribute__((ext_vector_type(4)));
typedef float f32x4 __attribute__((ext_vector_type(4)));
typedef _Float16 f16;
typedef f16 f16x2 __attribute__((ext_vector_type(2)));
typedef f16 f16x4 __attribute__((ext_vector_type(4)));

__device__ __forceinline__ float wave_sum(float v){
  #pragma unroll
  for (int off = 32; off; off >>= 1) v += __shfl_xor(v, off, 64);
  return v;
}
__device__ __forceinline__ float wave_max(float v){
  #pragma unroll
  for (int off = 32; off; off >>= 1) v = fmaxf(v, __shfl_xor(v, off, 64));
  return v;
}

__device__ __forceinline__ void async16(const bf16* g, bf16* l){
  __builtin_amdgcn_global_load_lds((const __attribute__((address_space(1))) unsigned int*)g,
                                   (__attribute__((address_space(3))) unsigned int*)l,
                                   16, 0, 0);
}

// ---------------- K0: normalize codebook rows v[64][384] -> clusb (bf16) ------------
__global__ __launch_bounds__(256) void k0_clusters(const float* __restrict__ vin,
                                                   bf16* __restrict__ clusb){
  int w = threadIdx.x >> 6, l = threadIdx.x & 63;
  int k = blockIdx.x * 4 + w;               // 16 blocks * 4 waves = 64 rows
  float s = 0.f;
  #pragma unroll
  for (int i = 0; i < 6; i++){ float x = vin[k*DD + l + 64*i]; s += x*x; }
  s = wave_sum(s);
  float scale = 1.f / fmaxf(sqrtf(s), 1e-12f);
  #pragma unroll
  for (int i = 0; i < 6; i++) clusb[k*DD + l + 64*i] = (bf16)(vin[k*DD + l + 64*i] * scale);
}

// ---------------- KW: convert conv_w fp32[384][768] -> bf16 ----------------
__global__ __launch_bounds__(256) void k_wconv(const float* __restrict__ w,
                                               bf16* __restrict__ wb){
  int i = (blockIdx.x * 256 + threadIdx.x) * 4;
  float4 v = *(const float4*)&w[i];
  bf16x4 o;
  o[0] = (bf16)v.x; o[1] = (bf16)v.y; o[2] = (bf16)v.z; o[3] = (bf16)v.w;
  *(bf16x4*)&wb[i] = o;
}

// ---------------- K1: fused GEMM front-end (v2).
// xp[b][n][m] = sum_c X[b][c][n]*W[m][c] + bias[m]; rn fused; xnb = bf16(xp*rn).
// Tile 64n x 384m, grid (16 x 32) = 512 blocks (2 blocks/CU -> 16 waves/CU).
// X staged fp32 in Xf[64][32] with float4-block XOR swizzle:
//   phys(c,n) = (((c>>2) ^ ((n>>3)&7))<<2) | (c&3); addr = n*32 + phys.
//   writes: phys bijective per 32-lane half -> 2-way b32 (free).
//   reads: 8 bank-groups x 8 lanes per b128 = hw minimum (conflict-free).
// X is reg-staged (T14): next step's float4 issues right after barrier B and
// its latency hides under the MFMA phase (reg loads aren't barrier-drained;
// only the L2-resident W global_load_lds is).
__global__ __launch_bounds__(512) void k_gemm(const bf16* __restrict__ Wb,
                                              const float* __restrict__ X,
                                              const float* __restrict__ bias,
                                              float* __restrict__ xp,
                                              bf16* __restrict__ xnb){
  __shared__ bf16  Wl[384][4][8];     // 24 KB
  __shared__ float Xf[64 * 32];       // 8 KB, swizzled
  __shared__ float part[4][64];       // per-wm row sumsq partials
  __shared__ float rn_l[64];
  int b  = blockIdx.y;
  int n0 = blockIdx.x * 64;
  int t = threadIdx.x, wv = t >> 6, l = t & 63;
  int l15 = l & 15, quad = l >> 4;
  int wn = wv >> 2, wm = wv & 3;
  const float* Xg = X + (size_t)b * CC * HWN;

  // W staging: chunk = t + 512*ii -> row = t>>2 + 128*ii, kq = t&3 (lane-linear LDS)
  const bf16* gW = Wb + (size_t)(t >> 2) * CC + (t & 3) * 8;
  bf16* lW = &Wl[0][0][0] + wv * 512;

  // X staging: c = t>>4 (0..31), n4 = (t&15)*4
  int cs = t >> 4, n4 = (t & 15) * 4;
  const float* gX = Xg + n0 + n4;
  int pw = (t & 15) >> 1;                                   // (n>>3)&7 for j<4
  int physw = ((((cs >> 2) ^ pw) & 7) << 2) | (cs & 3);
  float* xw = &Xf[n4 * 32 + physw];

  f32x4 acc[2][6];
  const f32x4 zero = {0.f, 0.f, 0.f, 0.f};
  #pragma unroll
  for (int i = 0; i < 2; i++)
    #pragma unroll
    for (int j = 0; j < 6; j++) acc[i][j] = zero;

  float4 xv = *(const float4*)(gX + (size_t)cs * HWN);      // prologue: step 0

  for (int c0 = 0; c0 < CC; c0 += 32){
    __syncthreads();                                        // A: prev reads done
    xw[0] = xv.x; xw[32] = xv.y; xw[64] = xv.z; xw[96] = xv.w;
    async16(gW + c0,                  lW);
    async16(gW + c0 + (size_t)128*CC, lW + 4096);
    async16(gW + c0 + (size_t)256*CC, lW + 8192);
    __syncthreads();                                        // B: drains W + ds writes
    if (c0 + 32 < CC)
      xv = *(const float4*)(gX + (size_t)(c0 + 32 + cs) * HWN);  // T14 prefetch

    bf16x8 xf[2], wf[6];
    #pragma unroll
    for (int i = 0; i < 2; i++){
      int nloc = wn*32 + i*16 + l15;
      int p = (nloc >> 3) & 7;
      const float4 f0 = *(const float4*)&Xf[nloc*32 + (((2*quad + 0) ^ p) << 2)];
      const float4 f1 = *(const float4*)&Xf[nloc*32 + (((2*quad + 1) ^ p) << 2)];
      bf16x8 c8;
      c8[0] = (bf16)f0.x; c8[1] = (bf16)f0.y; c8[2] = (bf16)f0.z; c8[3] = (bf16)f0.w;
      c8[4] = (bf16)f1.x; c8[5] = (bf16)f1.y; c8[6] = (bf16)f1.z; c8[7] = (bf16)f1.w;
      xf[i] = c8;
    }
    #pragma unroll
    for (int j = 0; j < 6; j++)
      wf[j] = *(const bf16x8*)&Wl[wm*96 + j*16 + l15][quad][0];
    #pragma unroll
    for (int i = 0; i < 2; i++)
      #pragma unroll
      for (int j = 0; j < 6; j++)
        acc[i][j] = __builtin_amdgcn_mfma_f32_16x16x32_bf16(xf[i], wf[j], acc[i][j], 0, 0, 0);
  }

  float bb[6];
  #pragma unroll
  for (int j = 0; j < 6; j++) bb[j] = bias[wm*96 + j*16 + l15];

  // ---- rnorm: per-row sumsq (j-sum, l15-reduce, cross-wm via LDS)
  #pragma unroll
  for (int i = 0; i < 2; i++){
    #pragma unroll
    for (int r = 0; r < 4; r++){
      float s = 0.f;
      #pragma unroll
      for (int j = 0; j < 6; j++){ float v = acc[i][j][r] + bb[j]; s = fmaf(v, v, s); }
      s += __shfl_xor(s, 1, 64); s += __shfl_xor(s, 2, 64);
      s += __shfl_xor(s, 4, 64); s += __shfl_xor(s, 8, 64);
      if (l15 == 0) part[wm][wn*32 + i*16 + quad*4 + r] = s;
    }
  }
  __syncthreads();
  if (t < 64){
    float tot = part[0][t] + part[1][t] + part[2][t] + part[3][t];
    rn_l[t] = 1.f / fmaxf(sqrtf(tot), 1e-12f);
  }
  __syncthreads();

  // ---- write xp fp32 + xnb bf16
  #pragma unroll
  for (int i = 0; i < 2; i++){
    #pragma unroll
    for (int r = 0; r < 4; r++){
      int nloc = wn*32 + i*16 + quad*4 + r;
      float rv = rn_l[nloc];
      float* orow = xp  + ((size_t)b * HWN + n0 + nloc) * DD;
      bf16*  xrow = xnb + ((size_t)b * HWN + n0 + nloc) * DD;
      #pragma unroll
      for (int j = 0; j < 6; j++){
        int m = wm*96 + j*16 + l15;
        float val = acc[i][j][r] + bb[j];
        orow[m] = val;
        xrow[m] = (bf16)(val * rv);
      }
    }
  }
}

// ---------------- KXPT2: bf16 transpose  XpT[b][d][n] = xnb[b][n][d] ----------------
__global__ __launch_bounds__(256) void k_xpt2(const bf16* __restrict__ xnb,
                                              bf16* __restrict__ xpt){
  __shared__ bf16 S[64][72];   // pad 8 bf16 (row 144B)
  int b  = blockIdx.z;
  int d0 = blockIdx.y * 64;
  int n0 = blockIdx.x * 64;
  const bf16* src = xnb + ((size_t)b * HWN + n0) * DD + d0;
  int t = threadIdx.x;
  int r = t >> 3, c8 = (t & 7) * 8;
  #pragma unroll
  for (int it = 0; it < 2; it++){
    bf16x8 v = *(const bf16x8*)&src[(size_t)(r + it*32) * DD + c8];
    *(bf16x8*)&S[r + it*32][c8] = v;
  }
  __syncthreads();
  int d = t >> 2, c0 = (t & 3) * 16;
  bf16* orow = xpt + ((size_t)b * DD + d0 + d) * HWN + n0 + c0;
  bf16x8 o0, o1;
  #pragma unroll
  for (int jj = 0; jj < 8; jj++) o0[jj] = S[c0 + jj][d];
  #pragma unroll
  for (int jj = 0; jj < 8; jj++) o1[jj] = S[c0 + 8 + jj][d];
  *(bf16x8*)&orow[0] = o0;
  *(bf16x8*)&orow[8] = o1;
}

// ---------------- K3 (MFMA): Z[b][k][n] = (clusb[k][:] . xnb[n][:]) * EPSI ----------
__global__ __launch_bounds__(256) void k3_scores(const bf16* __restrict__ clusb,
                                                 const bf16* __restrict__ xnb,
                                                 float* __restrict__ Z){
  __shared__ bf16 Al[64][4][8];    // 4 KB  clusters slab
  __shared__ bf16 Bl[128][4][8];   // 8 KB  xn slab
  int b = blockIdx.y, n0 = blockIdx.x * 128;
  const bf16* Xb = xnb + (size_t)b * HWN * DD;
  int t = threadIdx.x, wv = t >> 6, l = t & 63;
  int l15 = l & 15, quad = l >> 4;

  int rbase = wv*16 + (l >> 2);
  int kq8   = (l & 3) * 8;
  const bf16* gA = clusb + (size_t)rbase * DD + kq8;
  const bf16* gB = Xb + (size_t)(n0 + rbase) * DD + kq8;
  bf16* lA = &Al[0][0][0] + wv * 512;
  bf16* lB = &Bl[0][0][0] + wv * 512;

  f32x4 acc[4][2];
  const f32x4 zero = {0.f, 0.f, 0.f, 0.f};
  #pragma unroll
  for (int i = 0; i < 4; i++){ acc[i][0] = zero; acc[i][1] = zero; }

  for (int d0 = 0; d0 < DD; d0 += 32){
    async16(gA + d0, lA);
    async16(gB + d0,                 lB);
    async16(gB + d0 + (size_t)64*DD, lB + 2048);
    __syncthreads();
    bf16x8 af[4], bf[2];
    #pragma unroll
    for (int i = 0; i < 4; i++)
      af[i] = *(const bf16x8*)&Al[i*16 + l15][quad][0];
    #pragma unroll
    for (int j = 0; j < 2; j++)
      bf[j] = *(const bf16x8*)&Bl[wv*32 + j*16 + l15][quad][0];
    #pragma unroll
    for (int i = 0; i < 4; i++)
      #pragma unroll
      for (int j = 0; j < 2; j++)
        acc[i][j] = __builtin_amdgcn_mfma_f32_16x16x32_bf16(af[i], bf[j], acc[i][j], 0, 0, 0);
    __syncthreads();
  }
  #pragma unroll
  for (int i = 0; i < 4; i++){
    #pragma unroll
    for (int j = 0; j < 2; j++){
      int n = n0 + wv*32 + j*16 + l15;
      #pragma unroll
      for (int r = 0; r < 4; r++){
        int k = i*16 + quad*4 + r;
        Z[((size_t)b*KK + k)*HWN + n] = acc[i][j][r] * EPSI;
      }
    }
  }
}

// ---------------- K4: Sinkhorn, one 1024-thr block per batch, E=exp(Z-rmax) in f16 LDS
// u[r] = NORMC - rmax[r] - log(sum_n E[r][n]*ev[n]);  eu[r] = exp(NORMC)/sum  (exact)
// v[c] = NORMC - log(sum_m E[m][c]*eu[m]);            ev[c] = exp(v[c])
// NOTE: v reaches ~+12 (asymmetric marginals 64 vs 1024) -> ev MUST be fp32.
// E in (0,1] is always f16-safe. ~145 KB LDS (gfx950: 160 KB/CU).
__global__ __launch_bounds__(1024) void k4_sinkhorn(const float* __restrict__ Z,
                                                    float* __restrict__ U,
                                                    float* __restrict__ V){
  __shared__ f16  E[64][1024];    // 128 KB
  __shared__ float evf[1024];     // exp(v), fp32 (overflow-safe)
  __shared__ float eu[64];
  __shared__ float rmax[64];
  __shared__ float u_l[64];
  __shared__ float v_l[1024];
  __shared__ float sp[2][1024];   // v-phase partials per column (two row-halves)
  int b = blockIdx.x;
  const float* Zb = Z + (size_t)b * KK * HWN;
  int t = threadIdx.x, w = t >> 6, l = t & 63;

  #pragma unroll
  for (int rr = 0; rr < 4; rr++){
    int r = w*4 + rr;
    float4 z[4];
    float mx = -INFINITY;
    #pragma unroll
    for (int j = 0; j < 4; j++){
      z[j] = *(const float4*)&Zb[(size_t)r*HWN + 4*l + 256*j];
      mx = fmaxf(mx, fmaxf(fmaxf(z[j].x, z[j].y), fmaxf(z[j].z, z[j].w)));
    }
    mx = wave_max(mx);
    if (l == 0) rmax[r] = mx;
    #pragma unroll
    for (int j = 0; j < 4; j++){
      f16x4 e4;
      e4[0] = (f16)__expf(z[j].x - mx); e4[1] = (f16)__expf(z[j].y - mx);
      e4[2] = (f16)__expf(z[j].z - mx); e4[3] = (f16)__expf(z[j].w - mx);
      *(f16x4*)&E[r][4*l + 256*j] = e4;
    }
  }
  evf[t] = 1.f;
  v_l[t] = 0.f;
  __syncthreads();

  for (int it = 0; it < NITERS; it++){
    float evx[16];
    #pragma unroll
    for (int j = 0; j < 8; j++){
      float2 e2 = *(const float2*)&evf[2*(l + 64*j)];
      evx[2*j] = e2.x; evx[2*j+1] = e2.y;
    }
    float us[4];
    #pragma unroll
    for (int rr = 0; rr < 4; rr++){
      int r = w*4 + rr;
      float s = 0.f;
      #pragma unroll
      for (int j = 0; j < 8; j++){
        f16x2 e2 = *(const f16x2*)&E[r][2*(l + 64*j)];
        s = fmaf((float)e2[0], evx[2*j],   s);
        s = fmaf((float)e2[1], evx[2*j+1], s);
      }
      us[rr] = wave_sum(s);
    }
    if (l == 0){
      #pragma unroll
      for (int rr = 0; rr < 4; rr++){
        int r = w*4 + rr;
        u_l[r] = NORMC - rmax[r] - __logf(us[rr]);
        eu[r]  = __expf(NORMC) / us[rr];
      }
    }
    __syncthreads();
    {
      int p = t & 511, h = t >> 9;
      float sx = 0.f, sy = 0.f;
      #pragma unroll
      for (int mq = 0; mq < 8; mq++){
        float4 eu4 = *(const float4*)&eu[h*32 + mq*4];
        const float euv[4] = {eu4.x, eu4.y, eu4.z, eu4.w};
        #pragma unroll
        for (int i = 0; i < 4; i++){
          f16x2 e2 = *(const f16x2*)&E[h*32 + mq*4 + i][2*p];
          sx = fmaf((float)e2[0], euv[i], sx);
          sy = fmaf((float)e2[1], euv[i], sy);
        }
      }
      float2 o; o.x = sx; o.y = sy;
      *(float2*)&sp[h][2*p] = o;
    }
    __syncthreads();
    if (t < 512){
      int p = t;
      float2 a = *(const float2*)&sp[0][2*p];
      float2 c = *(const float2*)&sp[1][2*p];
      float vx = NORMC - __logf(a.x + c.x);
      float vy = NORMC - __logf(a.y + c.y);
      v_l[2*p]   = vx;
      v_l[2*p+1] = vy;
      float2 ee; ee.x = __expf(vx); ee.y = __expf(vy);
      *(float2*)&evf[2*p] = ee;
    }
    __syncthreads();
  }
  V[b*HWN + t] = v_l[t];
  if (t < 64) U[b*KK + t] = u_l[t];
}

// ---------------- K5 (MFMA, split-K over n): out[b][k][d] += sum_n E'[k][n]*XpT[d][n]
// E'[k][n] = exp(Z+u+v-NORMC) in bf16 (rn already folded into XpT).
// Grid (8 chunks x 32 b) = 256 blocks; 4 n-steps of 32 per block; atomic partials.
__global__ __launch_bounds__(256) void k5_mfma(const float* __restrict__ Z,
                                               const float* __restrict__ U,
                                               const float* __restrict__ V,
                                               const bf16* __restrict__ XpT,
                                               float* __restrict__ out){
  __shared__ bf16 El[64][40];     // 5 KB   [k][n-step]
  __shared__ bf16 Xl[384][40];    // 30 KB  [d][n-step]
  int b  = blockIdx.y;
  int nsb = blockIdx.x * 128;     // n-chunk base
  const float* Zb = Z + (size_t)b * KK * HWN;
  const bf16*  Xb = XpT + (size_t)b * DD * HWN;
  const float* Vb = V + (size_t)b * HWN;
  int t = threadIdx.x, wv = t >> 6, l = t & 63;
  int l15 = l & 15, quad = l >> 4;
  int er = t >> 2, ec0 = (t & 3) * 8;
  float ur = U[b*KK + er];

  f32x4 acc[4][6];
  const f32x4 zero = {0.f, 0.f, 0.f, 0.f};
  #pragma unroll
  for (int i = 0; i < 4; i++)
    #pragma unroll
    for (int j = 0; j < 6; j++) acc[i][j] = zero;

  for (int st = 0; st < 4; st++){
    int n0 = nsb + st*32;
    {
      float4 z0 = *(const float4*)&Zb[(size_t)er*HWN + n0 + ec0];
      float4 z1 = *(const float4*)&Zb[(size_t)er*HWN + n0 + ec0 + 4];
      float4 v0 = *(const float4*)&Vb[n0 + ec0];
      float4 v1 = *(const float4*)&Vb[n0 + ec0 + 4];
      bf16x8 e;
      e[0] = (bf16)__expf(z0.x + ur + v0.x - NORMC);
      e[1] = (bf16)__expf(z0.y + ur + v0.y - NORMC);
      e[2] = (bf16)__expf(z0.z + ur + v0.z - NORMC);
      e[3] = (bf16)__expf(z0.w + ur + v0.w - NORMC);
      e[4] = (bf16)__expf(z1.x + ur + v1.x - NORMC);
      e[5] = (bf16)__expf(z1.y + ur + v1.y - NORMC);
      e[6] = (bf16)__expf(z1.z + ur + v1.z - NORMC);
      e[7] = (bf16)__expf(z1.w + ur + v1.w - NORMC);
      *(bf16x8*)&El[er][ec0] = e;
    }
    #pragma unroll
    for (int ii = 0; ii < 6; ii++){
      int chunk = t + 256*ii;
      int d = chunk >> 2, cb = (chunk & 3) * 8;
      bf16x8 xv = *(const bf16x8*)&Xb[(size_t)d*HWN + n0 + cb];
      *(bf16x8*)&Xl[d][cb] = xv;
    }
    __syncthreads();
    bf16x8 af[4], bfr[6];
    #pragma unroll
    for (int i = 0; i < 4; i++)
      af[i] = *(const bf16x8*)&El[i*16 + l15][quad*8];
    #pragma unroll
    for (int j = 0; j < 6; j++)
      bfr[j] = *(const bf16x8*)&Xl[wv*96 + j*16 + l15][quad*8];
    #pragma unroll
    for (int i = 0; i < 4; i++)
      #pragma unroll
      for (int j = 0; j < 6; j++)
        acc[i][j] = __builtin_amdgcn_mfma_f32_16x16x32_bf16(af[i], bfr[j], acc[i][j], 0, 0, 0);
    __syncthreads();
  }

  float* ob = out + (size_t)b * KK * DD;
  #pragma unroll
  for (int i = 0; i < 4; i++){
    int kbase = i*16 + quad*4;
    #pragma unroll
    for (int j = 0; j < 6; j++){
      int d = wv*96 + j*16 + l15;
      #pragma unroll
      for (int r = 0; r < 4; r++)
        unsafeAtomicAdd(&ob[(size_t)(kbase + r)*DD + d], acc[i][j][r]);
    }
  }
}

extern "C" void kernel_launch(void* const* d_in, const int* in_sizes, int n_in,
                              void* d_out, int out_size, void* d_ws, size_t ws_size,
                              hipStream_t stream) {
  const float* x      = (const float*)d_in[0];   // [32,768,32,32]
  const float* conv_w = (const float*)d_in[1];   // [384,768]
  const float* conv_b = (const float*)d_in[2];   // [384]
  const float* vcode  = (const float*)d_in[3];   // [64,384]
  float* out = (float*)d_out;
  float* vt_out = out;                 // [32,64,384]  = 786432
  float* xp_out = out + 786432;        // [32,1024,384]

  bf16* xnb   = (bf16*)d_ws;                         // 12,582,912 bf16 (25.2 MB)
  bf16* XpT   = xnb + (size_t)BB * HWN * DD;         // 12,582,912 bf16 (25.2 MB)
  bf16* Wb    = XpT + (size_t)BB * HWN * DD;         // 294,912 bf16
  bf16* clusb = Wb + (size_t)DD * CC;                // 24,576 bf16
  float* Zbuf = (float*)(clusb + 24576);             // 2,097,152 f32
  float* Ubuf = Zbuf + 2097152;                      // 2,048
  float* Vbuf = Ubuf + 2048;                         // 32,768

  hipMemsetAsync(vt_out, 0, (size_t)786432 * sizeof(float), stream);
  k0_clusters<<<16, 256, 0, stream>>>(vcode, clusb);
  k_wconv<<<288, 256, 0, stream>>>(conv_w, Wb);
  k_gemm<<<dim3(16, 32), 512, 0, stream>>>(Wb, x, conv_b, xp_out, xnb);
  k_xpt2<<<dim3(16, 6, 32), 256, 0, stream>>>(xnb, XpT);
  k3_scores<<<dim3(8, 32), 256, 0, stream>>>(clusb, xnb, Zbuf);
  k4_sinkhorn<<<32, 1024, 0, stream>>>(Zbuf, Ubuf, Vbuf);
  k5_mfma<<<dim3(8, 32), 256, 0, stream>>>(Zbuf, Ubuf, Vbuf, XpT, vt_out);
}